// Round 5
// baseline (241.768 us; speedup 1.0000x reference)
//
#include <hip/hip_runtime.h>

#define DEV __device__ __forceinline__

constexpr int A_ = 64, DE = 128, M_ = 512, DH = 64;

DEV float wred_sum64(float v) {
#pragma unroll
    for (int o = 1; o < 64; o <<= 1) v += __shfl_xor(v, o, 64);
    return v;
}

// ---------------- Kernel 1: per-(b,m) hyperbolic dH2 + log_map ----------------
__global__ __launch_bounds__(256) void k_hyp(const float* __restrict__ curr_hyp,
                                             const float* __restrict__ demo_hyp,
                                             float* __restrict__ dH2,
                                             float* __restrict__ logv) {
    const int lane = threadIdx.x & 63;
    const int r    = (blockIdx.x << 2) + (threadIdx.x >> 6);  // [0, B*M)
    const int b    = r >> 9;                                  // M=512

    float x = curr_hyp[(b << 6) + lane];
    float y = demo_hyp[((size_t)r << 6) + lane];
    const float mx = 1.0f - 1e-5f;

    float x2r = wred_sum64(x * x);
    float xn  = fmaxf(sqrtf(x2r), 1e-15f);
    float sx  = xn > mx ? mx / xn : 1.0f;
    x *= sx;
    float x2 = x2r * sx * sx;
    float y2r = wred_sum64(y * y);
    float yn  = fmaxf(sqrtf(y2r), 1e-15f);
    float sy  = yn > mx ? mx / yn : 1.0f;
    y *= sy;
    float y2 = y2r * sy * sy;

    float xy = wred_sum64(x * y);
    float num = (1.f - 2.f * xy + y2) * (-x) + (1.f - x2) * y;
    float den = fmaxf(1.f - 2.f * xy + x2 * y2, 1e-15f);
    float u   = num / den;

    float u2  = wred_sum64(u * u);
    float un  = fmaxf(sqrtf(u2), 1e-15f);
    float arg = fminf(un, 1.f - 1e-7f);
    float at  = 0.5f * __logf((1.f + arg) / (1.f - arg));  // atanh

    if (lane == 0) dH2[r] = 4.f * at * at;

    float lamden = fmaxf(1.f - x2, 1e-15f);  // 2/lambda
    float ls     = lamden * at / un;
    logv[((size_t)r << 6) + lane] = ls * u;
}

// ---------------- Kernel 2: FULLY-contiguous streaming (fill-like) ----------------
// grid = B*32 blocks (b = blk>>5, mc = blk&31); 1024 threads.
// Block streams demo_rho[b, mc*16 : mc*16+16, :, :] == 512 KB SEQUENTIAL (the block
// owns ALL 64 a's for its 16 m-rows; no other block touches this span).
// Thread (a = t>>4, dp = t&15) owns column a, de dims [dp*8, dp*8+8).
// Per-thread flash over its 16 m's; NO intra-block combine (a wholly thread-owned).
// All partials written TRANSPOSED to [b][a][...] so k_comb3 reads contiguously.
__global__ __launch_bounds__(1024) void k_stream3(const float* __restrict__ curr_rho,
                                                  const float* __restrict__ demo_rho,
                                                  const float* __restrict__ dH2,
                                                  float* __restrict__ ws_m,
                                                  float* __restrict__ ws_s,
                                                  float* __restrict__ ws_e,
                                                  float* __restrict__ ws_sc) {
    const int t   = threadIdx.x;
    const int mi  = t >> 4;   // a
    const int dp  = t & 15;
    const int blk = blockIdx.x;
    const int b   = blk >> 5, mc = blk & 31;
    const int m0  = mc << 4;

    float qf[8];
    {
        const float* qp = curr_rho + ((size_t)(b * 64 + mi)) * DE + dp * 8;
        float4 q0 = *(const float4*)qp;
        float4 q1 = *(const float4*)(qp + 4);
        qf[0] = q0.x; qf[1] = q0.y; qf[2] = q0.z; qf[3] = q0.w;
        qf[4] = q1.x; qf[5] = q1.y; qf[6] = q1.z; qf[7] = q1.w;
    }

    float dh2r[16];
    {
        const float* dp2 = dH2 + (b << 9) + m0;
        *(float4*)&dh2r[0]  = *(const float4*)(dp2);
        *(float4*)&dh2r[4]  = *(const float4*)(dp2 + 4);
        *(float4*)&dh2r[8]  = *(const float4*)(dp2 + 8);
        *(float4*)&dh2r[12] = *(const float4*)(dp2 + 12);
    }

    // m-row = A_*DE = 8192 floats = 32 KB; block walks 16 consecutive rows
    const float* tp = demo_rho + ((size_t)(b * M_ + m0)) * (A_ * DE) + mi * DE + dp * 8;

    // depth-3 register prefetch pipeline
    float4 pa0 = *(const float4*)tp;
    float4 pa1 = *(const float4*)(tp + 4);
    float4 pb0 = *(const float4*)(tp + 8192);
    float4 pb1 = *(const float4*)(tp + 8192 + 4);
    float4 pc0 = *(const float4*)(tp + 16384);
    float4 pc1 = *(const float4*)(tp + 16384 + 4);

    float e_acc[8];
#pragma unroll
    for (int j = 0; j < 8; j++) e_acc[j] = 0.f;
    float gmax = -1e30f, gsum = 0.f;

    float* scp = ws_sc + ((size_t)(b * 64 + mi)) * 512 + m0;  // [b][a][m]

#pragma unroll
    for (int c = 0; c < 16; ++c) {
        float4 n0 = make_float4(0.f, 0.f, 0.f, 0.f);
        float4 n1 = n0;
        if (c + 3 < 16) {
            const float* np = tp + (size_t)(c + 3) * 8192;
            n0 = *(const float4*)np;
            n1 = *(const float4*)(np + 4);
        }
        float kf[8];
        kf[0] = pa0.x; kf[1] = pa0.y; kf[2] = pa0.z; kf[3] = pa0.w;
        kf[4] = pa1.x; kf[5] = pa1.y; kf[6] = pa1.z; kf[7] = pa1.w;

        float ps = 0.f;
#pragma unroll
        for (int j = 0; j < 8; j++) { float d = qf[j] - kf[j]; ps += d * d; }
        ps += __shfl_xor(ps, 1, 64);
        ps += __shfl_xor(ps, 2, 64);
        ps += __shfl_xor(ps, 4, 64);
        ps += __shfl_xor(ps, 8, 64);  // uniform over the 16-lane dp group

        float sc = -(dh2r[c] + ps);
        if (dp == 0) scp[c] = sc;     // [b][a][m] : combine reads 2KB contiguous

        // per-thread online flash (state uniform within dp-group)
        float gnew = fmaxf(gmax, sc);
        float r1   = __expf(gmax - gnew);   // c==0: exp(-inf)=0
        float w    = __expf(sc - gnew);
        gsum = fmaf(gsum, r1, w);
#pragma unroll
        for (int j = 0; j < 8; j++) e_acc[j] = fmaf(w, kf[j], e_acc[j] * r1);
        gmax = gnew;

        pa0 = pb0; pa1 = pb1; pb0 = pc0; pb1 = pc1; pc0 = n0; pc1 = n1;
    }

    // write unnormalized partials, transposed: ws_e[b][a][mc][d]
    float* ep = ws_e + (((size_t)(b * 64 + mi)) * 32 + mc) * 128 + dp * 8;
    *(float4*)ep       = make_float4(e_acc[0], e_acc[1], e_acc[2], e_acc[3]);
    *(float4*)(ep + 4) = make_float4(e_acc[4], e_acc[5], e_acc[6], e_acc[7]);
    if (dp == 0) {
        ws_m[(b * 64 + mi) * 32 + mc] = gmax;   // [b][a][mc]
        ws_s[(b * 64 + mi) * 32 + mc] = gsum;
    }
}

// ---------------- Kernel 3: 32-way flash merge + v + exp_map + matmul + LN ----------------
// one block per (b,a); 256 threads = 4 waves. All partial reads CONTIGUOUS per block.
__global__ __launch_bounds__(256) void k_comb3(const float* __restrict__ curr_hyp,
                                               const float* __restrict__ logv,
                                               const float* __restrict__ ws_m,
                                               const float* __restrict__ ws_s,
                                               const float* __restrict__ ws_e,
                                               const float* __restrict__ ws_sc,
                                               const float* __restrict__ We,
                                               const float* __restrict__ Wh,
                                               const float* __restrict__ gamma,
                                               const float* __restrict__ beta,
                                               float* __restrict__ out) {
    __shared__ float facL[32];
    __shared__ float sMS[2];
    __shared__ float wL[512];      // exp(sc[m]-M)
    __shared__ float ehL[192];     // [0:128) e_out, [128:192) h
    __shared__ float vpart[4][64];

    const int t   = threadIdx.x;
    const int blk = blockIdx.x;
    const int b   = blk >> 6, a = blk & 63;
    const size_t ba = (size_t)(b * 64 + a);

    // ---- step 1: merge the 32 per-chunk flash states (contiguous 128B reads) ----
    float g = -1e30f, s = 0.f;
    if (t < 32) {
        g = ws_m[ba * 32 + t];
        s = ws_s[ba * 32 + t];
    }
    float M = g;
    M = fmaxf(M, __shfl_xor(M, 1, 64));
    M = fmaxf(M, __shfl_xor(M, 2, 64));
    M = fmaxf(M, __shfl_xor(M, 4, 64));
    M = fmaxf(M, __shfl_xor(M, 8, 64));
    M = fmaxf(M, __shfl_xor(M, 16, 64));   // lanes 0..31 hold full max
    float fac = __expf(g - M);
    float Sp  = s * fac;
    Sp += __shfl_xor(Sp, 1, 64);
    Sp += __shfl_xor(Sp, 2, 64);
    Sp += __shfl_xor(Sp, 4, 64);
    Sp += __shfl_xor(Sp, 8, 64);
    Sp += __shfl_xor(Sp, 16, 64);
    if (t < 32) facL[t] = fac;
    if (t == 0) { sMS[0] = M; sMS[1] = Sp; }
    __syncthreads();
    const float Mg   = sMS[0];
    const float invS = 1.f / sMS[1];

    // ---- step 2: e_out[d] = sum_mc e[mc][d]*fac[mc] / S  (16KB contiguous block) ----
    if (t < 128) {
        const float* eb = ws_e + ba * (32 * 128) + t;
        float acc = 0.f;
#pragma unroll
        for (int mc = 0; mc < 32; ++mc)
            acc = fmaf(eb[mc * 128], facL[mc], acc);
        ehL[t] = acc * invS;
    }

    // ---- step 2b: stage w[m] = exp(sc[m]-M) (2KB contiguous read) ----
    {
        float2 scv = ((const float2*)(ws_sc + ba * 512))[t];
        wL[2 * t]     = __expf(scv.x - Mg);
        wL[2 * t + 1] = __expf(scv.y - Mg);
    }
    __syncthreads();

    // ---- step 3: v[dh] = sum_m w[m]*logv[m][dh] (4 waves, 128 m each) ----
    {
        const int dh = t & 63, sg = t >> 6;
        const float* lvb = logv + ((size_t)(b * M_ + sg * 128)) * 64 + dh;
        float vac = 0.f;
#pragma unroll 8
        for (int i = 0; i < 128; ++i)
            vac = fmaf(wL[sg * 128 + i], lvb[(size_t)i * 64], vac);
        vpart[sg][dh] = vac;
    }
    __syncthreads();

    // ---- step 4: exp_map + We/Wh matmul + LN (wave 0) ----
    if (t < 64) {
        const int lane = t;
        float v = (vpart[0][lane] + vpart[1][lane] + vpart[2][lane] + vpart[3][lane]) * invS;

        const float mx = 1.0f - 1e-5f;
        float x = curr_hyp[(b << 6) + lane];
        float x2r = wred_sum64(x * x);
        float xn  = fmaxf(sqrtf(x2r), 1e-15f);
        float sx  = xn > mx ? mx / xn : 1.f;
        x *= sx;
        float x2 = x2r * sx * sx;
        float lamden = fmaxf(1.f - x2, 1e-15f);  // 2/lambda

        float v2 = wred_sum64(v * v);
        float vn = fmaxf(sqrtf(v2), 1e-15f);
        float targ   = vn / lamden;              // lambda*vnorm/2
        float e2     = __expf(2.f * targ);
        float factor = 1.f - 2.f / (e2 + 1.f);   // tanh, inf-safe
        float wvv    = v * (factor / vn);

        float w2 = wred_sum64(wvv * wvv);
        float xw = wred_sum64(x * wvv);
        float num = (1.f + 2.f * xw + w2) * x + (1.f - x2) * wvv;
        float den = fmaxf(1.f + 2.f * xw + x2 * w2, 1e-15f);
        float h   = num / den;
        float h2  = wred_sum64(h * h);
        float hn  = fmaxf(sqrtf(h2), 1e-15f);
        float shh = hn > mx ? mx / hn : 1.f;
        h *= shh;
        ehL[128 + lane] = h;  // same-wave visibility

        float ze = 0.f;
        const float* werow = We + lane * 128;
#pragma unroll
        for (int d0 = 0; d0 < 128; d0 += 4) {
            float4 wv4 = *(const float4*)(werow + d0);
            ze = fmaf(ehL[d0 + 0], wv4.x, ze);
            ze = fmaf(ehL[d0 + 1], wv4.y, ze);
            ze = fmaf(ehL[d0 + 2], wv4.z, ze);
            ze = fmaf(ehL[d0 + 3], wv4.w, ze);
        }
        float zh = 0.f;
        const float* whrow = Wh + lane * 64;
#pragma unroll
        for (int d0 = 0; d0 < 64; d0 += 4) {
            float4 wv4 = *(const float4*)(whrow + d0);
            zh = fmaf(ehL[128 + d0 + 0], wv4.x, zh);
            zh = fmaf(ehL[128 + d0 + 1], wv4.y, zh);
            zh = fmaf(ehL[128 + d0 + 2], wv4.z, zh);
            zh = fmaf(ehL[128 + d0 + 3], wv4.w, zh);
        }
        float ssum = wred_sum64(ze + zh);
        float mean = ssum * (1.f / 128.f);
        float sq   = wred_sum64(ze * ze + zh * zh);
        float var  = sq * (1.f / 128.f) - mean * mean;
        float rinv = rsqrtf(var + 1e-5f);
        float oe = (ze - mean) * rinv * gamma[lane] + beta[lane];
        float oh = (zh - mean) * rinv * gamma[64 + lane] + beta[64 + lane];
        out[(size_t)blk * 128 + lane]      = oe;
        out[(size_t)blk * 128 + 64 + lane] = oh;
    }
}

extern "C" void kernel_launch(void* const* d_in, const int* in_sizes, int n_in,
                              void* d_out, int out_size, void* d_ws, size_t ws_size,
                              hipStream_t stream) {
    const float* curr_rho = (const float*)d_in[0];
    const float* curr_hyp = (const float*)d_in[1];
    const float* demo_rho = (const float*)d_in[2];
    const float* demo_hyp = (const float*)d_in[3];
    const float* We       = (const float*)d_in[4];
    const float* Wh       = (const float*)d_in[5];
    const float* gamma    = (const float*)d_in[6];
    const float* beta     = (const float*)d_in[7];
    float* out = (float*)d_out;

    // workspace (floats), total 2,658,304 = 10.63 MB — proven available in round 3
    float* ws    = (float*)d_ws;
    float* dH2   = ws;             // 4096
    float* logv  = ws + 4096;      // 262144  [b][m][dh]
    float* ws_m  = ws + 266240;    // 16384   [b][a][mc]
    float* ws_s  = ws + 282624;    // 16384   [b][a][mc]
    float* ws_e  = ws + 299008;    // 2097152 [b][a][mc][d]
    float* ws_sc = ws + 2396160;   // 262144  [b][a][m]

    k_hyp<<<1024, 256, 0, stream>>>(curr_hyp, demo_hyp, dH2, logv);
    k_stream3<<<256, 1024, 0, stream>>>(curr_rho, demo_rho, dH2, ws_m, ws_s, ws_e, ws_sc);
    k_comb3<<<512, 256, 0, stream>>>(curr_hyp, logv, ws_m, ws_s, ws_e, ws_sc,
                                     We, Wh, gamma, beta, out);
}

// Round 6
// 224.666 us; speedup vs baseline: 1.0761x; 1.0761x over previous
//
#include <hip/hip_runtime.h>

#define DEV __device__ __forceinline__

constexpr int A_ = 64, DE = 128, M_ = 512, DH = 64;

DEV float wred_sum64(float v) {
#pragma unroll
    for (int o = 1; o < 64; o <<= 1) v += __shfl_xor(v, o, 64);
    return v;
}

// ---------------- Kernel 1: per-(b,m) hyperbolic dH2 + log_map ----------------
__global__ __launch_bounds__(256) void k_hyp(const float* __restrict__ curr_hyp,
                                             const float* __restrict__ demo_hyp,
                                             float* __restrict__ dH2,
                                             float* __restrict__ logv) {
    const int lane = threadIdx.x & 63;
    const int r    = (blockIdx.x << 2) + (threadIdx.x >> 6);  // [0, B*M)
    const int b    = r >> 9;                                  // M=512

    float x = curr_hyp[(b << 6) + lane];
    float y = demo_hyp[((size_t)r << 6) + lane];
    const float mx = 1.0f - 1e-5f;

    float x2r = wred_sum64(x * x);
    float xn  = fmaxf(sqrtf(x2r), 1e-15f);
    float sx  = xn > mx ? mx / xn : 1.0f;
    x *= sx;
    float x2 = x2r * sx * sx;
    float y2r = wred_sum64(y * y);
    float yn  = fmaxf(sqrtf(y2r), 1e-15f);
    float sy  = yn > mx ? mx / yn : 1.0f;
    y *= sy;
    float y2 = y2r * sy * sy;

    float xy = wred_sum64(x * y);
    float num = (1.f - 2.f * xy + y2) * (-x) + (1.f - x2) * y;
    float den = fmaxf(1.f - 2.f * xy + x2 * y2, 1e-15f);
    float u   = num / den;

    float u2  = wred_sum64(u * u);
    float un  = fmaxf(sqrtf(u2), 1e-15f);
    float arg = fminf(un, 1.f - 1e-7f);
    float at  = 0.5f * __logf((1.f + arg) / (1.f - arg));  // atanh

    if (lane == 0) dH2[r] = 4.f * at * at;

    float lamden = fmaxf(1.f - x2, 1e-15f);  // 2/lambda
    float ls     = lamden * at / un;
    logv[((size_t)r << 6) + lane] = ls * u;
}

// ---------------- Kernel 2: round-1 streamer, m-split x2 for 4 blocks/CU ----------------
// grid = 1024 blocks: blk = (b*64+a)*2 + h ; h = m-half (256 m's). 512 threads = 8 waves.
// Thread (mi = t>>4 chunk-local m, dp = t&15 d-octet) — identical to round-1 mapping.
// Per-wave online flash; 8-wave LDS combine; 2 partials per (b,a) to workspace.
__global__ __launch_bounds__(512, 8) void k_ms(const float* __restrict__ curr_rho,
                                               const float* __restrict__ demo_rho,
                                               const float* __restrict__ dH2,
                                               float* __restrict__ ws_m,
                                               float* __restrict__ ws_s,
                                               float* __restrict__ ws_e,
                                               float* __restrict__ ws_sc) {
    __shared__ float lds_dh[256];
    __shared__ float redm[8];
    __shared__ float reds[8];
    __shared__ __align__(16) float rede[32 * 132];

    const int t    = threadIdx.x;
    const int lane = t & 63;
    const int wv   = t >> 6;
    const int dp   = t & 15;
    const int mi   = t >> 4;          // 0..31
    const int blk  = blockIdx.x;      // (b*64+a)*2 + h
    const int h    = blk & 1;
    const int ba   = blk >> 1;        // b*64 + a
    const int b    = ba >> 6, a = ba & 63;

    if (t < 256) lds_dh[t] = dH2[(b << 9) + (h << 8) + t];

    float qf[8];
    {
        const float* qp = curr_rho + (size_t)ba * DE + dp * 8;
        float4 q0 = *(const float4*)qp;
        float4 q1 = *(const float4*)(qp + 4);
        qf[0] = q0.x; qf[1] = q0.y; qf[2] = q0.z; qf[3] = q0.w;
        qf[4] = q1.x; qf[5] = q1.y; qf[6] = q1.z; qf[7] = q1.w;
    }

    const size_t rowStride = (size_t)A_ * DE;        // 8192 floats
    const size_t cstep     = (size_t)32 * rowStride; // 32 m-rows per chunk
    const float* tp = demo_rho + ((size_t)(b * M_ + h * 256) * A_ + a) * DE
                    + (size_t)mi * rowStride + dp * 8;

    __syncthreads();  // lds_dh

    // depth-2 register prefetch (round-1 proven)
    float4 ka0 = *(const float4*)tp;
    float4 ka1 = *(const float4*)(tp + 4);
    float4 kb0 = *(const float4*)(tp + cstep);
    float4 kb1 = *(const float4*)(tp + cstep + 4);

    float e_acc[8];
#pragma unroll
    for (int j = 0; j < 8; j++) e_acc[j] = 0.f;
    float gmax = -1e30f, gsum = 0.f;  // per-WAVE flash state

#pragma unroll 2
    for (int c = 0; c < 8; ++c) {
        float4 n0, n1;
        if (c + 2 < 8) {
            const float* np = tp + (size_t)(c + 2) * cstep;
            n0 = *(const float4*)np;
            n1 = *(const float4*)(np + 4);
        }
        float kf[8];
        kf[0] = ka0.x; kf[1] = ka0.y; kf[2] = ka0.z; kf[3] = ka0.w;
        kf[4] = ka1.x; kf[5] = ka1.y; kf[6] = ka1.z; kf[7] = ka1.w;

        float ps = 0.f;
#pragma unroll
        for (int j = 0; j < 8; j++) { float d = qf[j] - kf[j]; ps += d * d; }
        ps += __shfl_xor(ps, 1, 64);
        ps += __shfl_xor(ps, 2, 64);
        ps += __shfl_xor(ps, 4, 64);
        ps += __shfl_xor(ps, 8, 64);  // uniform over dp-group
        float sc = -(lds_dh[c * 32 + mi] + ps);
        if (dp == 0)
            ws_sc[(size_t)ba * M_ + h * 256 + c * 32 + mi] = sc;  // [b][a][m]

        // per-wave online flash over the wave's 4 m's (lane bits 4,5)
        float lm = fmaxf(sc, __shfl_xor(sc, 16, 64));
        lm = fmaxf(lm, __shfl_xor(lm, 32, 64));
        float gnew = fmaxf(gmax, lm);
        float r1   = __expf(gmax - gnew);    // c==0: exp(-inf)=0
        float wexp = __expf(sc - gnew);
        float wsum = wexp + __shfl_xor(wexp, 16, 64);
        wsum += __shfl_xor(wsum, 32, 64);
        gsum = fmaf(gsum, r1, wsum);
#pragma unroll
        for (int j = 0; j < 8; j++) e_acc[j] = fmaf(wexp, kf[j], e_acc[j] * r1);
        gmax = gnew;

        ka0 = kb0; ka1 = kb1; kb0 = n0; kb1 = n1;
    }

    // ---- combine the 8 waves' flash states ----
    if (lane == 0) { redm[wv] = gmax; reds[wv] = gsum; }
    __syncthreads();

    float Mb = redm[0];
#pragma unroll
    for (int w = 1; w < 8; w++) Mb = fmaxf(Mb, redm[w]);
    float Sb = 0.f;
#pragma unroll
    for (int w = 0; w < 8; w++) Sb += reds[w] * __expf(redm[w] - Mb);
    const float fac = __expf(gmax - Mb);  // wave-uniform rescale

    *(float4*)&rede[mi * 132 + dp * 8] =
        make_float4(e_acc[0] * fac, e_acc[1] * fac, e_acc[2] * fac, e_acc[3] * fac);
    *(float4*)&rede[mi * 132 + dp * 8 + 4] =
        make_float4(e_acc[4] * fac, e_acc[5] * fac, e_acc[6] * fac, e_acc[7] * fac);
    if (t == 0) { ws_m[blk] = Mb; ws_s[blk] = Sb; }
    __syncthreads();

    if (t < 128) {
        float s = 0.f;
#pragma unroll
        for (int g = 0; g < 32; g++) s += rede[g * 132 + t];
        ws_e[(size_t)blk * 128 + t] = s;  // unnormalized, scaled to Mb
    }
}

// ---------------- Kernel 3: 2-way flash merge + v + exp_map + matmul + LN ----------------
// one block per (b,a); 256 threads = 4 waves. (Tail identical to round-5's — ~2-3 us.)
__global__ __launch_bounds__(256) void k_comb_s(const float* __restrict__ curr_hyp,
                                                const float* __restrict__ logv,
                                                const float* __restrict__ ws_m,
                                                const float* __restrict__ ws_s,
                                                const float* __restrict__ ws_e,
                                                const float* __restrict__ ws_sc,
                                                const float* __restrict__ We,
                                                const float* __restrict__ Wh,
                                                const float* __restrict__ gamma,
                                                const float* __restrict__ beta,
                                                float* __restrict__ out) {
    __shared__ float wL[512];      // exp(sc[m]-M)
    __shared__ float ehL[192];     // [0:128) e_out, [128:192) h
    __shared__ float vpart[4][64];

    const int t   = threadIdx.x;
    const int blk = blockIdx.x;
    const int b   = blk >> 6, a = blk & 63;
    const size_t ba = (size_t)blk;

    // ---- step 1: merge the 2 half flash states (uniform scalar loads) ----
    const float m0 = ws_m[ba * 2], m1 = ws_m[ba * 2 + 1];
    const float s0 = ws_s[ba * 2], s1 = ws_s[ba * 2 + 1];
    const float M  = fmaxf(m0, m1);
    const float f0 = __expf(m0 - M), f1 = __expf(m1 - M);
    const float invS = 1.f / (s0 * f0 + s1 * f1);

    // ---- step 2: e_out[d] (two contiguous 512B partial rows) ----
    if (t < 128) {
        float acc = ws_e[ba * 256 + t] * f0 + ws_e[ba * 256 + 128 + t] * f1;
        ehL[t] = acc * invS;
    }

    // ---- step 2b: w[m] = exp(sc[m]-M), 2KB contiguous (same-wave write/read) ----
    {
        float2 scv = ((const float2*)(ws_sc + ba * 512))[t];
        wL[2 * t]     = __expf(scv.x - M);
        wL[2 * t + 1] = __expf(scv.y - M);
    }

    // ---- step 3: v[dh] = sum_m w[m]*logv[m][dh] (4 waves, 128 m each) ----
    {
        const int dh = t & 63, sg = t >> 6;
        const float* lvb = logv + ((size_t)(b * M_ + sg * 128)) * 64 + dh;
        float vac = 0.f;
#pragma unroll 8
        for (int i = 0; i < 128; ++i)
            vac = fmaf(wL[sg * 128 + i], lvb[(size_t)i * 64], vac);
        vpart[sg][dh] = vac;
    }
    __syncthreads();

    // ---- step 4: exp_map + We/Wh matmul + LN (wave 0) ----
    if (t < 64) {
        const int lane = t;
        float v = (vpart[0][lane] + vpart[1][lane] + vpart[2][lane] + vpart[3][lane]) * invS;

        const float mx = 1.0f - 1e-5f;
        float x = curr_hyp[(b << 6) + lane];
        float x2r = wred_sum64(x * x);
        float xn  = fmaxf(sqrtf(x2r), 1e-15f);
        float sx  = xn > mx ? mx / xn : 1.f;
        x *= sx;
        float x2 = x2r * sx * sx;
        float lamden = fmaxf(1.f - x2, 1e-15f);  // 2/lambda

        float v2 = wred_sum64(v * v);
        float vn = fmaxf(sqrtf(v2), 1e-15f);
        float targ   = vn / lamden;              // lambda*vnorm/2
        float e2     = __expf(2.f * targ);
        float factor = 1.f - 2.f / (e2 + 1.f);   // tanh, inf-safe
        float wvv    = v * (factor / vn);

        float w2 = wred_sum64(wvv * wvv);
        float xw = wred_sum64(x * wvv);
        float num = (1.f + 2.f * xw + w2) * x + (1.f - x2) * wvv;
        float den = fmaxf(1.f + 2.f * xw + x2 * w2, 1e-15f);
        float hh  = num / den;
        float h2  = wred_sum64(hh * hh);
        float hn  = fmaxf(sqrtf(h2), 1e-15f);
        float shh = hn > mx ? mx / hn : 1.f;
        hh *= shh;
        ehL[128 + lane] = hh;  // same-wave visibility

        float ze = 0.f;
        const float* werow = We + lane * 128;
#pragma unroll
        for (int d0 = 0; d0 < 128; d0 += 4) {
            float4 wv4 = *(const float4*)(werow + d0);
            ze = fmaf(ehL[d0 + 0], wv4.x, ze);
            ze = fmaf(ehL[d0 + 1], wv4.y, ze);
            ze = fmaf(ehL[d0 + 2], wv4.z, ze);
            ze = fmaf(ehL[d0 + 3], wv4.w, ze);
        }
        float zh = 0.f;
        const float* whrow = Wh + lane * 64;
#pragma unroll
        for (int d0 = 0; d0 < 64; d0 += 4) {
            float4 wv4 = *(const float4*)(whrow + d0);
            zh = fmaf(ehL[128 + d0 + 0], wv4.x, zh);
            zh = fmaf(ehL[128 + d0 + 1], wv4.y, zh);
            zh = fmaf(ehL[128 + d0 + 2], wv4.z, zh);
            zh = fmaf(ehL[128 + d0 + 3], wv4.w, zh);
        }
        float ssum = wred_sum64(ze + zh);
        float mean = ssum * (1.f / 128.f);
        float sq   = wred_sum64(ze * ze + zh * zh);
        float var  = sq * (1.f / 128.f) - mean * mean;
        float rinv = rsqrtf(var + 1e-5f);
        float oe = (ze - mean) * rinv * gamma[lane] + beta[lane];
        float oh = (zh - mean) * rinv * gamma[64 + lane] + beta[64 + lane];
        out[(size_t)blk * 128 + lane]      = oe;
        out[(size_t)blk * 128 + 64 + lane] = oh;
    }
}

extern "C" void kernel_launch(void* const* d_in, const int* in_sizes, int n_in,
                              void* d_out, int out_size, void* d_ws, size_t ws_size,
                              hipStream_t stream) {
    const float* curr_rho = (const float*)d_in[0];
    const float* curr_hyp = (const float*)d_in[1];
    const float* demo_rho = (const float*)d_in[2];
    const float* demo_hyp = (const float*)d_in[3];
    const float* We       = (const float*)d_in[4];
    const float* Wh       = (const float*)d_in[5];
    const float* gamma    = (const float*)d_in[6];
    const float* beta     = (const float*)d_in[7];
    float* out = (float*)d_out;

    // workspace (floats): total 661,504 = 2.65 MB (well under proven 10.6 MB)
    float* ws    = (float*)d_ws;
    float* dH2   = ws;             // 4096
    float* logv  = ws + 4096;      // 262144  [b][m][dh]
    float* ws_m  = ws + 266240;    // 1024    [b][a][h]
    float* ws_s  = ws + 267264;    // 1024
    float* ws_e  = ws + 268288;    // 131072  [b][a][h][d]
    float* ws_sc = ws + 399360;    // 262144  [b][a][m]

    k_hyp<<<1024, 256, 0, stream>>>(curr_hyp, demo_hyp, dH2, logv);
    k_ms<<<1024, 512, 0, stream>>>(curr_rho, demo_rho, dH2, ws_m, ws_s, ws_e, ws_sc);
    k_comb_s<<<512, 256, 0, stream>>>(curr_hyp, logv, ws_m, ws_s, ws_e, ws_sc,
                                      We, Wh, gamma, beta, out);
}

// Round 7
// 216.774 us; speedup vs baseline: 1.1153x; 1.0364x over previous
//
#include <hip/hip_runtime.h>

#define DEV __device__ __forceinline__

constexpr int A_ = 64, DE = 128, M_ = 512, DH = 64;

DEV float wred_sum64(float v) {
#pragma unroll
    for (int o = 1; o < 64; o <<= 1) v += __shfl_xor(v, o, 64);
    return v;
}

// ---------------- Kernel 1: per-(b,m) hyperbolic dH2 + log_map ----------------
__global__ __launch_bounds__(256) void k_hyp(const float* __restrict__ curr_hyp,
                                             const float* __restrict__ demo_hyp,
                                             float* __restrict__ dH2,
                                             float* __restrict__ logv) {
    const int lane = threadIdx.x & 63;
    const int r    = (blockIdx.x << 2) + (threadIdx.x >> 6);  // [0, B*M)
    const int b    = r >> 9;                                  // M=512

    float x = curr_hyp[(b << 6) + lane];
    float y = demo_hyp[((size_t)r << 6) + lane];
    const float mx = 1.0f - 1e-5f;

    float x2r = wred_sum64(x * x);
    float xn  = fmaxf(sqrtf(x2r), 1e-15f);
    float sx  = xn > mx ? mx / xn : 1.0f;
    x *= sx;
    float x2 = x2r * sx * sx;
    float y2r = wred_sum64(y * y);
    float yn  = fmaxf(sqrtf(y2r), 1e-15f);
    float sy  = yn > mx ? mx / yn : 1.0f;
    y *= sy;
    float y2 = y2r * sy * sy;

    float xy = wred_sum64(x * y);
    float num = (1.f - 2.f * xy + y2) * (-x) + (1.f - x2) * y;
    float den = fmaxf(1.f - 2.f * xy + x2 * y2, 1e-15f);
    float u   = num / den;

    float u2  = wred_sum64(u * u);
    float un  = fmaxf(sqrtf(u2), 1e-15f);
    float arg = fminf(un, 1.f - 1e-7f);
    float at  = 0.5f * __logf((1.f + arg) / (1.f - arg));  // atanh

    if (lane == 0) dH2[r] = 4.f * at * at;

    float lamden = fmaxf(1.f - x2, 1e-15f);  // 2/lambda
    float ls     = lamden * at / un;
    logv[((size_t)r << 6) + lane] = ls * u;
}

// ---------------- Kernel 2: r1 streamer, m-split x2, r1 register budget ----------------
// grid = 1024 blocks: blk = (b*64+a)*2 + h ; h = m-half (256 m's). 512 threads = 8 waves.
// IDENTICAL inner loop to round-1 (the 209.9us best). Changes vs round 6:
//   * __launch_bounds__(512,4)  — restore r1's VGPR budget (r6's (512,8) squeezed to 64)
//   * ws_sc buffered in LDS, written as one dense 1KB store (kills write amplification)
__global__ __launch_bounds__(512, 4) void k_ms(const float* __restrict__ curr_rho,
                                               const float* __restrict__ demo_rho,
                                               const float* __restrict__ dH2,
                                               float* __restrict__ ws_m,
                                               float* __restrict__ ws_s,
                                               float* __restrict__ ws_e,
                                               float* __restrict__ ws_sc) {
    __shared__ float lds_dh[256];
    __shared__ float lds_sc[256];
    __shared__ float redm[8];
    __shared__ float reds[8];
    __shared__ __align__(16) float rede[32 * 132];

    const int t    = threadIdx.x;
    const int lane = t & 63;
    const int wv   = t >> 6;
    const int dp   = t & 15;
    const int mi   = t >> 4;          // 0..31
    const int blk  = blockIdx.x;      // (b*64+a)*2 + h
    const int h    = blk & 1;
    const int ba   = blk >> 1;        // b*64 + a
    const int b    = ba >> 6, a = ba & 63;

    if (t < 256) lds_dh[t] = dH2[(b << 9) + (h << 8) + t];

    float qf[8];
    {
        const float* qp = curr_rho + (size_t)ba * DE + dp * 8;
        float4 q0 = *(const float4*)qp;
        float4 q1 = *(const float4*)(qp + 4);
        qf[0] = q0.x; qf[1] = q0.y; qf[2] = q0.z; qf[3] = q0.w;
        qf[4] = q1.x; qf[5] = q1.y; qf[6] = q1.z; qf[7] = q1.w;
    }

    const size_t rowStride = (size_t)A_ * DE;        // 8192 floats
    const size_t cstep     = (size_t)32 * rowStride; // 32 m-rows per chunk
    const float* tp = demo_rho + ((size_t)(b * M_ + h * 256) * A_ + a) * DE
                    + (size_t)mi * rowStride + dp * 8;

    __syncthreads();  // lds_dh

    // depth-2 register prefetch (round-1 proven)
    float4 ka0 = *(const float4*)tp;
    float4 ka1 = *(const float4*)(tp + 4);
    float4 kb0 = *(const float4*)(tp + cstep);
    float4 kb1 = *(const float4*)(tp + cstep + 4);

    float e_acc[8];
#pragma unroll
    for (int j = 0; j < 8; j++) e_acc[j] = 0.f;
    float gmax = -1e30f, gsum = 0.f;  // per-WAVE flash state

#pragma unroll 2
    for (int c = 0; c < 8; ++c) {
        float4 n0, n1;
        if (c + 2 < 8) {
            const float* np = tp + (size_t)(c + 2) * cstep;
            n0 = *(const float4*)np;
            n1 = *(const float4*)(np + 4);
        }
        float kf[8];
        kf[0] = ka0.x; kf[1] = ka0.y; kf[2] = ka0.z; kf[3] = ka0.w;
        kf[4] = ka1.x; kf[5] = ka1.y; kf[6] = ka1.z; kf[7] = ka1.w;

        float ps = 0.f;
#pragma unroll
        for (int j = 0; j < 8; j++) { float d = qf[j] - kf[j]; ps += d * d; }
        ps += __shfl_xor(ps, 1, 64);
        ps += __shfl_xor(ps, 2, 64);
        ps += __shfl_xor(ps, 4, 64);
        ps += __shfl_xor(ps, 8, 64);  // uniform over dp-group
        float sc = -(lds_dh[c * 32 + mi] + ps);
        if (dp == 0) lds_sc[c * 32 + mi] = sc;   // buffer; dense global write at end

        // per-wave online flash over the wave's 4 m's (lane bits 4,5)
        float lm = fmaxf(sc, __shfl_xor(sc, 16, 64));
        lm = fmaxf(lm, __shfl_xor(lm, 32, 64));
        float gnew = fmaxf(gmax, lm);
        float r1   = __expf(gmax - gnew);    // c==0: exp(-inf)=0
        float wexp = __expf(sc - gnew);
        float wsum = wexp + __shfl_xor(wexp, 16, 64);
        wsum += __shfl_xor(wsum, 32, 64);
        gsum = fmaf(gsum, r1, wsum);
#pragma unroll
        for (int j = 0; j < 8; j++) e_acc[j] = fmaf(wexp, kf[j], e_acc[j] * r1);
        gmax = gnew;

        ka0 = kb0; ka1 = kb1; kb0 = n0; kb1 = n1;
    }

    // ---- combine the 8 waves' flash states ----
    if (lane == 0) { redm[wv] = gmax; reds[wv] = gsum; }
    __syncthreads();

    float Mb = redm[0];
#pragma unroll
    for (int w = 1; w < 8; w++) Mb = fmaxf(Mb, redm[w]);
    float Sb = 0.f;
#pragma unroll
    for (int w = 0; w < 8; w++) Sb += reds[w] * __expf(redm[w] - Mb);
    const float fac = __expf(gmax - Mb);  // wave-uniform rescale

    *(float4*)&rede[mi * 132 + dp * 8] =
        make_float4(e_acc[0] * fac, e_acc[1] * fac, e_acc[2] * fac, e_acc[3] * fac);
    *(float4*)&rede[mi * 132 + dp * 8 + 4] =
        make_float4(e_acc[4] * fac, e_acc[5] * fac, e_acc[6] * fac, e_acc[7] * fac);
    if (t == 0) { ws_m[blk] = Mb; ws_s[blk] = Sb; }
    __syncthreads();

    if (t < 128) {
        float s = 0.f;
#pragma unroll
        for (int g = 0; g < 32; g++) s += rede[g * 132 + t];
        ws_e[(size_t)blk * 128 + t] = s;  // unnormalized, scaled to Mb
    }
    if (t < 256)  // dense 1KB store of this half's raw scores: [b][a][m]
        ws_sc[(size_t)ba * M_ + h * 256 + t] = lds_sc[t];
}

// ---------------- Kernel 3: 2-way flash merge + v + exp_map + matmul + LN ----------------
// one block per (b,a); 256 threads = 4 waves.
__global__ __launch_bounds__(256) void k_comb_s(const float* __restrict__ curr_hyp,
                                                const float* __restrict__ logv,
                                                const float* __restrict__ ws_m,
                                                const float* __restrict__ ws_s,
                                                const float* __restrict__ ws_e,
                                                const float* __restrict__ ws_sc,
                                                const float* __restrict__ We,
                                                const float* __restrict__ Wh,
                                                const float* __restrict__ gamma,
                                                const float* __restrict__ beta,
                                                float* __restrict__ out) {
    __shared__ float wL[512];      // exp(sc[m]-M)
    __shared__ float ehL[192];     // [0:128) e_out, [128:192) h
    __shared__ float vpart[4][64];

    const int t   = threadIdx.x;
    const int blk = blockIdx.x;
    const int b   = blk >> 6;
    const size_t ba = (size_t)blk;

    // ---- step 1: merge the 2 half flash states (uniform scalar loads) ----
    const float m0 = ws_m[ba * 2], m1 = ws_m[ba * 2 + 1];
    const float s0 = ws_s[ba * 2], s1 = ws_s[ba * 2 + 1];
    const float M  = fmaxf(m0, m1);
    const float f0 = __expf(m0 - M), f1 = __expf(m1 - M);
    const float invS = 1.f / (s0 * f0 + s1 * f1);

    // ---- step 2: e_out[d] (two contiguous 512B partial rows) ----
    if (t < 128) {
        float acc = ws_e[ba * 256 + t] * f0 + ws_e[ba * 256 + 128 + t] * f1;
        ehL[t] = acc * invS;
    }

    // ---- step 2b: w[m] = exp(sc[m]-M), 2KB contiguous ----
    {
        float2 scv = ((const float2*)(ws_sc + ba * 512))[t];
        wL[2 * t]     = __expf(scv.x - M);
        wL[2 * t + 1] = __expf(scv.y - M);
    }
    __syncthreads();

    // ---- step 3: v[dh] = sum_m w[m]*logv[m][dh] (4 waves, 128 m each) ----
    {
        const int dh = t & 63, sg = t >> 6;
        const float* lvb = logv + ((size_t)(b * M_ + sg * 128)) * 64 + dh;
        float vac = 0.f;
#pragma unroll 8
        for (int i = 0; i < 128; ++i)
            vac = fmaf(wL[sg * 128 + i], lvb[(size_t)i * 64], vac);
        vpart[sg][dh] = vac;
    }
    __syncthreads();

    // ---- step 4: exp_map + We/Wh matmul + LN (wave 0) ----
    if (t < 64) {
        const int lane = t;
        float v = (vpart[0][lane] + vpart[1][lane] + vpart[2][lane] + vpart[3][lane]) * invS;

        const float mx = 1.0f - 1e-5f;
        float x = curr_hyp[(b << 6) + lane];
        float x2r = wred_sum64(x * x);
        float xn  = fmaxf(sqrtf(x2r), 1e-15f);
        float sx  = xn > mx ? mx / xn : 1.f;
        x *= sx;
        float x2 = x2r * sx * sx;
        float lamden = fmaxf(1.f - x2, 1e-15f);  // 2/lambda

        float v2 = wred_sum64(v * v);
        float vn = fmaxf(sqrtf(v2), 1e-15f);
        float targ   = vn / lamden;              // lambda*vnorm/2
        float e2     = __expf(2.f * targ);
        float factor = 1.f - 2.f / (e2 + 1.f);   // tanh, inf-safe
        float wvv    = v * (factor / vn);

        float w2 = wred_sum64(wvv * wvv);
        float xw = wred_sum64(x * wvv);
        float num = (1.f + 2.f * xw + w2) * x + (1.f - x2) * wvv;
        float den = fmaxf(1.f + 2.f * xw + x2 * w2, 1e-15f);
        float hh  = num / den;
        float h2  = wred_sum64(hh * hh);
        float hn  = fmaxf(sqrtf(h2), 1e-15f);
        float shh = hn > mx ? mx / hn : 1.f;
        hh *= shh;
        ehL[128 + lane] = hh;  // same-wave visibility

        float ze = 0.f;
        const float* werow = We + lane * 128;
#pragma unroll
        for (int d0 = 0; d0 < 128; d0 += 4) {
            float4 wv4 = *(const float4*)(werow + d0);
            ze = fmaf(ehL[d0 + 0], wv4.x, ze);
            ze = fmaf(ehL[d0 + 1], wv4.y, ze);
            ze = fmaf(ehL[d0 + 2], wv4.z, ze);
            ze = fmaf(ehL[d0 + 3], wv4.w, ze);
        }
        float zh = 0.f;
        const float* whrow = Wh + lane * 64;
#pragma unroll
        for (int d0 = 0; d0 < 64; d0 += 4) {
            float4 wv4 = *(const float4*)(whrow + d0);
            zh = fmaf(ehL[128 + d0 + 0], wv4.x, zh);
            zh = fmaf(ehL[128 + d0 + 1], wv4.y, zh);
            zh = fmaf(ehL[128 + d0 + 2], wv4.z, zh);
            zh = fmaf(ehL[128 + d0 + 3], wv4.w, zh);
        }
        float ssum = wred_sum64(ze + zh);
        float mean = ssum * (1.f / 128.f);
        float sq   = wred_sum64(ze * ze + zh * zh);
        float var  = sq * (1.f / 128.f) - mean * mean;
        float rinv = rsqrtf(var + 1e-5f);
        float oe = (ze - mean) * rinv * gamma[lane] + beta[lane];
        float oh = (zh - mean) * rinv * gamma[64 + lane] + beta[64 + lane];
        out[(size_t)blk * 128 + lane]      = oe;
        out[(size_t)blk * 128 + 64 + lane] = oh;
    }
}

extern "C" void kernel_launch(void* const* d_in, const int* in_sizes, int n_in,
                              void* d_out, int out_size, void* d_ws, size_t ws_size,
                              hipStream_t stream) {
    const float* curr_rho = (const float*)d_in[0];
    const float* curr_hyp = (const float*)d_in[1];
    const float* demo_rho = (const float*)d_in[2];
    const float* demo_hyp = (const float*)d_in[3];
    const float* We       = (const float*)d_in[4];
    const float* Wh       = (const float*)d_in[5];
    const float* gamma    = (const float*)d_in[6];
    const float* beta     = (const float*)d_in[7];
    float* out = (float*)d_out;

    // workspace (floats): total 661,504 = 2.65 MB
    float* ws    = (float*)d_ws;
    float* dH2   = ws;             // 4096
    float* logv  = ws + 4096;      // 262144  [b][m][dh]
    float* ws_m  = ws + 266240;    // 1024    [b][a][h]
    float* ws_s  = ws + 267264;    // 1024
    float* ws_e  = ws + 268288;    // 131072  [b][a][h][d]
    float* ws_sc = ws + 399360;    // 262144  [b][a][m]

    k_hyp<<<1024, 256, 0, stream>>>(curr_hyp, demo_hyp, dH2, logv);
    k_ms<<<1024, 512, 0, stream>>>(curr_rho, demo_rho, dH2, ws_m, ws_s, ws_e, ws_sc);
    k_comb_s<<<512, 256, 0, stream>>>(curr_hyp, logv, ws_m, ws_s, ws_e, ws_sc,
                                      We, Wh, gamma, beta, out);
}

// Round 8
// 213.261 us; speedup vs baseline: 1.1337x; 1.0165x over previous
//
#include <hip/hip_runtime.h>

#define DEV __device__ __forceinline__

constexpr int A_ = 64, DE = 128, M_ = 512, DH = 64;

DEV float wred_sum64(float v) {
#pragma unroll
    for (int o = 1; o < 64; o <<= 1) v += __shfl_xor(v, o, 64);
    return v;
}

// ---------------- Kernel 1: per-(b,m) hyperbolic dH2 + log_map ----------------
// one wave per (b,m) row; lane = dim (dh=64)
__global__ __launch_bounds__(256) void k_hyp(const float* __restrict__ curr_hyp,
                                             const float* __restrict__ demo_hyp,
                                             float* __restrict__ dH2,
                                             float* __restrict__ logv) {
    const int lane = threadIdx.x & 63;
    const int r    = (blockIdx.x << 2) + (threadIdx.x >> 6);  // [0, B*M)
    const int b    = r >> 9;                                  // M=512

    float x = curr_hyp[(b << 6) + lane];
    float y = demo_hyp[((size_t)r << 6) + lane];
    const float mx = 1.0f - 1e-5f;

    float x2r = wred_sum64(x * x);
    float xn  = fmaxf(sqrtf(x2r), 1e-15f);
    float sx  = xn > mx ? mx / xn : 1.0f;
    x *= sx;
    float x2 = x2r * sx * sx;
    float y2r = wred_sum64(y * y);
    float yn  = fmaxf(sqrtf(y2r), 1e-15f);
    float sy  = yn > mx ? mx / yn : 1.0f;
    y *= sy;
    float y2 = y2r * sy * sy;

    float xy = wred_sum64(x * y);
    float num = (1.f - 2.f * xy + y2) * (-x) + (1.f - x2) * y;
    float den = fmaxf(1.f - 2.f * xy + x2 * y2, 1e-15f);
    float u   = num / den;

    float u2  = wred_sum64(u * u);
    float un  = fmaxf(sqrtf(u2), 1e-15f);
    float arg = fminf(un, 1.f - 1e-7f);
    float at  = 0.5f * __logf((1.f + arg) / (1.f - arg));  // atanh

    if (lane == 0) dH2[r] = 4.f * at * at;

    float lamden = fmaxf(1.f - x2, 1e-15f);  // 2/lambda
    float ls     = lamden * at / un;
    logv[((size_t)r << 6) + lane] = ls * u;
}

// ---------------- Kernel 2: round-1 monolith, prefetch depth 2 -> 4 ----------------
// one block per (b,a); 512 threads = 8 waves. Identical to the 209.9us round-1 kernel
// in every respect except the register prefetch pipeline is depth-4 (4 KB in flight
// per wave, 64 KB/CU at 2 blocks/CU) to ride out loaded-HBM queueing latency.
__global__ __launch_bounds__(512, 4) void k_main(const float* __restrict__ curr_rho,
                                                 const float* __restrict__ demo_rho,
                                                 const float* __restrict__ curr_hyp,
                                                 const float* __restrict__ dH2,
                                                 const float* __restrict__ logv,
                                                 const float* __restrict__ We,
                                                 const float* __restrict__ Wh,
                                                 const float* __restrict__ gamma,
                                                 const float* __restrict__ beta,
                                                 float* __restrict__ out) {
    __shared__ __align__(16) float rede[32 * 132];  // e_acc reduce scratch, padded stride
    __shared__ float lds_sc[512];
    __shared__ float lds_dh[512];
    __shared__ float redm[8];
    __shared__ float reds[8];
    __shared__ float vpart[8][64];
    __shared__ float eh[192];  // [0:128) e_out, [128:192) h

    const int t    = threadIdx.x;
    const int lane = t & 63;
    const int wv   = t >> 6;
    const int dp   = t & 15;
    const int mi   = t >> 4;           // 0..31
    const int blk  = blockIdx.x;
    const int b    = blk >> 6, a = blk & 63;

    lds_dh[t] = dH2[(b << 9) + t];

    float qf[8];
    {
        float4 q0 = *(const float4*)(curr_rho + (size_t)blk * DE + dp * 8);
        float4 q1 = *(const float4*)(curr_rho + (size_t)blk * DE + dp * 8 + 4);
        qf[0] = q0.x; qf[1] = q0.y; qf[2] = q0.z; qf[3] = q0.w;
        qf[4] = q1.x; qf[5] = q1.y; qf[6] = q1.z; qf[7] = q1.w;
    }

    // per-thread streaming pointer: this thread's 32B slice of row mi of each chunk
    const size_t rowStride = (size_t)A_ * DE;        // 8192 floats
    const size_t cstep     = (size_t)32 * rowStride; // floats per 32-m chunk
    const float* tp = demo_rho + ((size_t)b * M_ * A_ + a) * DE + (size_t)mi * rowStride + dp * 8;

    __syncthreads();  // lds_dh visible to all waves (only pre-loop barrier)

    // depth-4 register prefetch pipeline (4 chunks in flight)
    float4 p0a = *(const float4*)tp;
    float4 p0b = *(const float4*)(tp + 4);
    float4 p1a = *(const float4*)(tp + cstep);
    float4 p1b = *(const float4*)(tp + cstep + 4);
    float4 p2a = *(const float4*)(tp + 2 * cstep);
    float4 p2b = *(const float4*)(tp + 2 * cstep + 4);
    float4 p3a = *(const float4*)(tp + 3 * cstep);
    float4 p3b = *(const float4*)(tp + 3 * cstep + 4);

    float e_acc[8];
#pragma unroll
    for (int j = 0; j < 8; j++) e_acc[j] = 0.f;
    float gmax = -1e30f, gsum = 0.f;  // per-WAVE running max/sum

#pragma unroll 4
    for (int c = 0; c < 16; ++c) {
        float4 n0, n1;
        if (c + 4 < 16) {  // issue chunk c+4 loads; 4 chunks stay in flight
            const float* np = tp + (size_t)(c + 4) * cstep;
            n0 = *(const float4*)np;
            n1 = *(const float4*)(np + 4);
        }
        float kf[8];
        kf[0] = p0a.x; kf[1] = p0a.y; kf[2] = p0a.z; kf[3] = p0a.w;
        kf[4] = p0b.x; kf[5] = p0b.y; kf[6] = p0b.z; kf[7] = p0b.w;

        float ps = 0.f;
#pragma unroll
        for (int j = 0; j < 8; j++) { float d = qf[j] - kf[j]; ps += d * d; }
        ps += __shfl_xor(ps, 1, 64);
        ps += __shfl_xor(ps, 2, 64);
        ps += __shfl_xor(ps, 4, 64);
        ps += __shfl_xor(ps, 8, 64);  // uniform over dp
        float sc = -(lds_dh[c * 32 + mi] + ps);
        if (dp == 0) lds_sc[c * 32 + mi] = sc;  // raw score for the v-step later

        // wave-local online softmax over this wave's 4 rows (lane bits 4,5)
        float lm = fmaxf(sc, __shfl_xor(sc, 16, 64));
        lm = fmaxf(lm, __shfl_xor(lm, 32, 64));
        float gnew = fmaxf(gmax, lm);
        float r1   = __expf(gmax - gnew);    // first chunk: exp(-inf)=0
        float wexp = __expf(sc - gnew);
        float wsum = wexp + __shfl_xor(wexp, 16, 64);
        wsum += __shfl_xor(wsum, 32, 64);
        gsum = fmaf(gsum, r1, wsum);
#pragma unroll
        for (int j = 0; j < 8; j++) e_acc[j] = fmaf(wexp, kf[j], e_acc[j] * r1);
        gmax = gnew;

        // rotate pipeline
        p0a = p1a; p0b = p1b;
        p1a = p2a; p1b = p2b;
        p2a = p3a; p2b = p3b;
        p3a = n0;  p3b = n1;
    }

    // ---- flash combine across the 8 waves ----
    if (lane == 0) { redm[wv] = gmax; reds[wv] = gsum; }
    __syncthreads();  // also covers lds_sc writes

    float M = redm[0];
#pragma unroll
    for (int w = 1; w < 8; w++) M = fmaxf(M, redm[w]);
    float S = 0.f;
#pragma unroll
    for (int w = 0; w < 8; w++) S += reds[w] * __expf(redm[w] - M);
    const float inv = 1.f / S;                 // block-uniform
    const float fw  = __expf(gmax - M);        // wave-uniform rescale of its partials

    float al = __expf(lds_sc[t] - M) * inv;    // alpha for own slot

    // reduce e_acc across the 32 mi-groups (pre-scaled by wave factor fw)
    *(float4*)&rede[mi * 132 + dp * 8] =
        make_float4(e_acc[0] * fw, e_acc[1] * fw, e_acc[2] * fw, e_acc[3] * fw);
    *(float4*)&rede[mi * 132 + dp * 8 + 4] =
        make_float4(e_acc[4] * fw, e_acc[5] * fw, e_acc[6] * fw, e_acc[7] * fw);
    lds_sc[t] = al;  // same-wave readers below
    __syncthreads();

    if (t < 128) {
        float s = 0.f;
#pragma unroll
        for (int g = 0; g < 32; g++) s += rede[g * 132 + t];
        eh[t] = s * inv;
    }

    // v = alpha @ logv : wave wv handles m in [wv*64, wv*64+64), lane = dh dim
    {
        const float* lvb = logv + ((size_t)(b * M_) + wv * 64) * DH;
        float acc = 0.f;
#pragma unroll 8
        for (int i = 0; i < 64; ++i)
            acc = fmaf(lds_sc[wv * 64 + i], lvb[(size_t)i * DH + lane], acc);
        vpart[wv][lane] = acc;
    }
    __syncthreads();

    if (wv == 0) {
        float v = 0.f;
#pragma unroll
        for (int w = 0; w < 8; w++) v += vpart[w][lane];

        const float mx = 1.0f - 1e-5f;
        float x = curr_hyp[(b << 6) + lane];
        float x2r = wred_sum64(x * x);
        float xn  = fmaxf(sqrtf(x2r), 1e-15f);
        float sx  = xn > mx ? mx / xn : 1.f;
        x *= sx;
        float x2 = x2r * sx * sx;
        float lamden = fmaxf(1.f - x2, 1e-15f);  // 2/lambda

        float v2 = wred_sum64(v * v);
        float vn = fmaxf(sqrtf(v2), 1e-15f);
        float targ   = vn / lamden;              // lambda*vnorm/2
        float e2     = __expf(2.f * targ);
        float factor = 1.f - 2.f / (e2 + 1.f);   // tanh, inf-safe
        float wvv    = v * (factor / vn);

        float w2 = wred_sum64(wvv * wvv);
        float xw = wred_sum64(x * wvv);
        float num = (1.f + 2.f * xw + w2) * x + (1.f - x2) * wvv;
        float den = fmaxf(1.f + 2.f * xw + x2 * w2, 1e-15f);
        float h   = num / den;
        float h2  = wred_sum64(h * h);
        float hn  = fmaxf(sqrtf(h2), 1e-15f);
        float shh = hn > mx ? mx / hn : 1.f;
        h *= shh;
        eh[128 + lane] = h;  // same-wave visibility

        float ze = 0.f;
        const float* werow = We + lane * 128;
#pragma unroll
        for (int d0 = 0; d0 < 128; d0 += 4) {
            float4 wv4 = *(const float4*)(werow + d0);
            ze = fmaf(eh[d0 + 0], wv4.x, ze);
            ze = fmaf(eh[d0 + 1], wv4.y, ze);
            ze = fmaf(eh[d0 + 2], wv4.z, ze);
            ze = fmaf(eh[d0 + 3], wv4.w, ze);
        }
        float zh = 0.f;
        const float* whrow = Wh + lane * 64;
#pragma unroll
        for (int d0 = 0; d0 < 64; d0 += 4) {
            float4 wv4 = *(const float4*)(whrow + d0);
            zh = fmaf(eh[128 + d0 + 0], wv4.x, zh);
            zh = fmaf(eh[128 + d0 + 1], wv4.y, zh);
            zh = fmaf(eh[128 + d0 + 2], wv4.z, zh);
            zh = fmaf(eh[128 + d0 + 3], wv4.w, zh);
        }
        float ssum = wred_sum64(ze + zh);
        float mean = ssum * (1.f / 128.f);
        float sq   = wred_sum64(ze * ze + zh * zh);
        float var  = sq * (1.f / 128.f) - mean * mean;
        float rinv = rsqrtf(var + 1e-5f);
        float oe = (ze - mean) * rinv * gamma[lane] + beta[lane];
        float oh = (zh - mean) * rinv * gamma[64 + lane] + beta[64 + lane];
        out[(size_t)blk * 128 + lane]      = oe;
        out[(size_t)blk * 128 + 64 + lane] = oh;
    }
}

extern "C" void kernel_launch(void* const* d_in, const int* in_sizes, int n_in,
                              void* d_out, int out_size, void* d_ws, size_t ws_size,
                              hipStream_t stream) {
    const float* curr_rho = (const float*)d_in[0];
    const float* curr_hyp = (const float*)d_in[1];
    const float* demo_rho = (const float*)d_in[2];
    const float* demo_hyp = (const float*)d_in[3];
    const float* We       = (const float*)d_in[4];
    const float* Wh       = (const float*)d_in[5];
    const float* gamma    = (const float*)d_in[6];
    const float* beta     = (const float*)d_in[7];
    float* out = (float*)d_out;

    float* ws   = (float*)d_ws;
    float* dH2  = ws;            // 4096 floats
    float* logv = ws + 4096;     // 262144 floats

    k_hyp<<<1024, 256, 0, stream>>>(curr_hyp, demo_hyp, dH2, logv);
    k_main<<<512, 512, 0, stream>>>(curr_rho, demo_rho, curr_hyp, dH2, logv,
                                    We, Wh, gamma, beta, out);
}

// Round 10
// 203.012 us; speedup vs baseline: 1.1909x; 1.0505x over previous
//
#include <hip/hip_runtime.h>

#define DEV __device__ __forceinline__

constexpr int A_ = 64, DE = 128, M_ = 512, DH = 64;

typedef float vf4 __attribute__((ext_vector_type(4)));  // native vector for nt builtins

DEV float wred_sum64(float v) {
#pragma unroll
    for (int o = 1; o < 64; o <<= 1) v += __shfl_xor(v, o, 64);
    return v;
}

DEV float4 nt_load4(const float* p) {
    vf4 r = __builtin_nontemporal_load((const vf4*)p);
    return make_float4(r.x, r.y, r.z, r.w);
}

// ---------------- Kernel 1: per-(b,m) hyperbolic dH2 + log_map ----------------
// one wave per (b,m) row; lane = dim (dh=64)
__global__ __launch_bounds__(256) void k_hyp(const float* __restrict__ curr_hyp,
                                             const float* __restrict__ demo_hyp,
                                             float* __restrict__ dH2,
                                             float* __restrict__ logv) {
    const int lane = threadIdx.x & 63;
    const int r    = (blockIdx.x << 2) + (threadIdx.x >> 6);  // [0, B*M)
    const int b    = r >> 9;                                  // M=512

    float x = curr_hyp[(b << 6) + lane];
    float y = demo_hyp[((size_t)r << 6) + lane];
    const float mx = 1.0f - 1e-5f;

    float x2r = wred_sum64(x * x);
    float xn  = fmaxf(sqrtf(x2r), 1e-15f);
    float sx  = xn > mx ? mx / xn : 1.0f;
    x *= sx;
    float x2 = x2r * sx * sx;
    float y2r = wred_sum64(y * y);
    float yn  = fmaxf(sqrtf(y2r), 1e-15f);
    float sy  = yn > mx ? mx / yn : 1.0f;
    y *= sy;
    float y2 = y2r * sy * sy;

    float xy = wred_sum64(x * y);
    float num = (1.f - 2.f * xy + y2) * (-x) + (1.f - x2) * y;
    float den = fmaxf(1.f - 2.f * xy + x2 * y2, 1e-15f);
    float u   = num / den;

    float u2  = wred_sum64(u * u);
    float un  = fmaxf(sqrtf(u2), 1e-15f);
    float arg = fminf(un, 1.f - 1e-7f);
    float at  = 0.5f * __logf((1.f + arg) / (1.f - arg));  // atanh

    if (lane == 0) dH2[r] = 4.f * at * at;

    float lamden = fmaxf(1.f - x2, 1e-15f);  // 2/lambda
    float ls     = lamden * at / un;
    logv[((size_t)r << 6) + lane] = ls * u;
}

// ---------------- Kernel 2: round-1 monolith + NONTEMPORAL streaming loads ----------------
// one block per (b,a); 512 threads = 8 waves. Byte-identical to the 209.9us round-1
// kernel except the six demo_rho load sites use nontemporal (no-allocate) loads:
// 134 MB of strictly zero-reuse data stops thrashing L1/L2.
__global__ __launch_bounds__(512, 4) void k_main(const float* __restrict__ curr_rho,
                                                 const float* __restrict__ demo_rho,
                                                 const float* __restrict__ curr_hyp,
                                                 const float* __restrict__ dH2,
                                                 const float* __restrict__ logv,
                                                 const float* __restrict__ We,
                                                 const float* __restrict__ Wh,
                                                 const float* __restrict__ gamma,
                                                 const float* __restrict__ beta,
                                                 float* __restrict__ out) {
    __shared__ __align__(16) float rede[32 * 132];  // e_acc reduce scratch, padded stride
    __shared__ float lds_sc[512];
    __shared__ float lds_dh[512];
    __shared__ float redm[8];
    __shared__ float reds[8];
    __shared__ float vpart[8][64];
    __shared__ float eh[192];  // [0:128) e_out, [128:192) h

    const int t    = threadIdx.x;
    const int lane = t & 63;
    const int wv   = t >> 6;
    const int dp   = t & 15;
    const int mi   = t >> 4;           // 0..31
    const int blk  = blockIdx.x;
    const int b    = blk >> 6, a = blk & 63;

    lds_dh[t] = dH2[(b << 9) + t];

    float qf[8];
    {
        float4 q0 = *(const float4*)(curr_rho + (size_t)blk * DE + dp * 8);
        float4 q1 = *(const float4*)(curr_rho + (size_t)blk * DE + dp * 8 + 4);
        qf[0] = q0.x; qf[1] = q0.y; qf[2] = q0.z; qf[3] = q0.w;
        qf[4] = q1.x; qf[5] = q1.y; qf[6] = q1.z; qf[7] = q1.w;
    }

    // per-thread streaming pointer: this thread's 32B slice of row mi of each chunk
    const size_t rowStride = (size_t)A_ * DE;        // 8192 floats
    const size_t cstep     = (size_t)32 * rowStride; // floats per 32-m chunk
    const float* tp = demo_rho + ((size_t)b * M_ * A_ + a) * DE + (size_t)mi * rowStride + dp * 8;

    __syncthreads();  // lds_dh visible to all waves (only pre-loop barrier)

    // depth-2 register prefetch pipeline (r1-proven), nontemporal loads
    float4 ka0 = nt_load4(tp);
    float4 ka1 = nt_load4(tp + 4);
    float4 kb0 = nt_load4(tp + cstep);
    float4 kb1 = nt_load4(tp + cstep + 4);

    float e_acc[8];
#pragma unroll
    for (int j = 0; j < 8; j++) e_acc[j] = 0.f;
    float gmax = -1e30f, gsum = 0.f;  // per-WAVE running max/sum

#pragma unroll 2
    for (int c = 0; c < 16; ++c) {
        float4 n0, n1;
        if (c + 2 < 16) {  // issue chunk c+2 loads; in flight across this chunk's compute
            const float* np = tp + (size_t)(c + 2) * cstep;
            n0 = nt_load4(np);
            n1 = nt_load4(np + 4);
        }
        float kf[8];
        kf[0] = ka0.x; kf[1] = ka0.y; kf[2] = ka0.z; kf[3] = ka0.w;
        kf[4] = ka1.x; kf[5] = ka1.y; kf[6] = ka1.z; kf[7] = ka1.w;

        float ps = 0.f;
#pragma unroll
        for (int j = 0; j < 8; j++) { float d = qf[j] - kf[j]; ps += d * d; }
        ps += __shfl_xor(ps, 1, 64);
        ps += __shfl_xor(ps, 2, 64);
        ps += __shfl_xor(ps, 4, 64);
        ps += __shfl_xor(ps, 8, 64);  // uniform over dp
        float sc = -(lds_dh[c * 32 + mi] + ps);
        if (dp == 0) lds_sc[c * 32 + mi] = sc;  // raw score for the v-step later

        // wave-local online softmax over this wave's 4 rows (lane bits 4,5)
        float lm = fmaxf(sc, __shfl_xor(sc, 16, 64));
        lm = fmaxf(lm, __shfl_xor(lm, 32, 64));
        float gnew = fmaxf(gmax, lm);
        float r1   = __expf(gmax - gnew);    // first chunk: exp(-inf)=0
        float wexp = __expf(sc - gnew);
        float wsum = wexp + __shfl_xor(wexp, 16, 64);
        wsum += __shfl_xor(wsum, 32, 64);
        gsum = fmaf(gsum, r1, wsum);
#pragma unroll
        for (int j = 0; j < 8; j++) e_acc[j] = fmaf(wexp, kf[j], e_acc[j] * r1);
        gmax = gnew;

        // rotate pipeline
        ka0 = kb0; ka1 = kb1; kb0 = n0; kb1 = n1;
    }

    // ---- flash combine across the 8 waves ----
    if (lane == 0) { redm[wv] = gmax; reds[wv] = gsum; }
    __syncthreads();  // also covers lds_sc writes

    float M = redm[0];
#pragma unroll
    for (int w = 1; w < 8; w++) M = fmaxf(M, redm[w]);
    float S = 0.f;
#pragma unroll
    for (int w = 0; w < 8; w++) S += reds[w] * __expf(redm[w] - M);
    const float inv = 1.f / S;                 // block-uniform
    const float fw  = __expf(gmax - M);        // wave-uniform rescale of its partials

    float al = __expf(lds_sc[t] - M) * inv;    // alpha for own slot

    // reduce e_acc across the 32 mi-groups (pre-scaled by wave factor fw)
    *(float4*)&rede[mi * 132 + dp * 8] =
        make_float4(e_acc[0] * fw, e_acc[1] * fw, e_acc[2] * fw, e_acc[3] * fw);
    *(float4*)&rede[mi * 132 + dp * 8 + 4] =
        make_float4(e_acc[4] * fw, e_acc[5] * fw, e_acc[6] * fw, e_acc[7] * fw);
    lds_sc[t] = al;  // same-wave readers below
    __syncthreads();

    if (t < 128) {
        float s = 0.f;
#pragma unroll
        for (int g = 0; g < 32; g++) s += rede[g * 132 + t];
        eh[t] = s * inv;
    }

    // v = alpha @ logv : wave wv handles m in [wv*64, wv*64+64), lane = dh dim
    {
        const float* lvb = logv + ((size_t)(b * M_) + wv * 64) * DH;
        float acc = 0.f;
#pragma unroll 8
        for (int i = 0; i < 64; ++i)
            acc = fmaf(lds_sc[wv * 64 + i], lvb[(size_t)i * DH + lane], acc);
        vpart[wv][lane] = acc;
    }
    __syncthreads();

    if (wv == 0) {
        float v = 0.f;
#pragma unroll
        for (int w = 0; w < 8; w++) v += vpart[w][lane];

        const float mx = 1.0f - 1e-5f;
        float x = curr_hyp[(b << 6) + lane];
        float x2r = wred_sum64(x * x);
        float xn  = fmaxf(sqrtf(x2r), 1e-15f);
        float sx  = xn > mx ? mx / xn : 1.f;
        x *= sx;
        float x2 = x2r * sx * sx;
        float lamden = fmaxf(1.f - x2, 1e-15f);  // 2/lambda

        float v2 = wred_sum64(v * v);
        float vn = fmaxf(sqrtf(v2), 1e-15f);
        float targ   = vn / lamden;              // lambda*vnorm/2
        float e2     = __expf(2.f * targ);
        float factor = 1.f - 2.f / (e2 + 1.f);   // tanh, inf-safe
        float wvv    = v * (factor / vn);

        float w2 = wred_sum64(wvv * wvv);
        float xw = wred_sum64(x * wvv);
        float num = (1.f + 2.f * xw + w2) * x + (1.f - x2) * wvv;
        float den = fmaxf(1.f + 2.f * xw + x2 * w2, 1e-15f);
        float h   = num / den;
        float h2  = wred_sum64(h * h);
        float hn  = fmaxf(sqrtf(h2), 1e-15f);
        float shh = hn > mx ? mx / hn : 1.f;
        h *= shh;
        eh[128 + lane] = h;  // same-wave visibility

        float ze = 0.f;
        const float* werow = We + lane * 128;
#pragma unroll
        for (int d0 = 0; d0 < 128; d0 += 4) {
            float4 wv4 = *(const float4*)(werow + d0);
            ze = fmaf(eh[d0 + 0], wv4.x, ze);
            ze = fmaf(eh[d0 + 1], wv4.y, ze);
            ze = fmaf(eh[d0 + 2], wv4.z, ze);
            ze = fmaf(eh[d0 + 3], wv4.w, ze);
        }
        float zh = 0.f;
        const float* whrow = Wh + lane * 64;
#pragma unroll
        for (int d0 = 0; d0 < 64; d0 += 4) {
            float4 wv4 = *(const float4*)(whrow + d0);
            zh = fmaf(eh[128 + d0 + 0], wv4.x, zh);
            zh = fmaf(eh[128 + d0 + 1], wv4.y, zh);
            zh = fmaf(eh[128 + d0 + 2], wv4.z, zh);
            zh = fmaf(eh[128 + d0 + 3], wv4.w, zh);
        }
        float ssum = wred_sum64(ze + zh);
        float mean = ssum * (1.f / 128.f);
        float sq   = wred_sum64(ze * ze + zh * zh);
        float var  = sq * (1.f / 128.f) - mean * mean;
        float rinv = rsqrtf(var + 1e-5f);
        float oe = (ze - mean) * rinv * gamma[lane] + beta[lane];
        float oh = (zh - mean) * rinv * gamma[64 + lane] + beta[64 + lane];
        out[(size_t)blk * 128 + lane]      = oe;
        out[(size_t)blk * 128 + 64 + lane] = oh;
    }
}

extern "C" void kernel_launch(void* const* d_in, const int* in_sizes, int n_in,
                              void* d_out, int out_size, void* d_ws, size_t ws_size,
                              hipStream_t stream) {
    const float* curr_rho = (const float*)d_in[0];
    const float* curr_hyp = (const float*)d_in[1];
    const float* demo_rho = (const float*)d_in[2];
    const float* demo_hyp = (const float*)d_in[3];
    const float* We       = (const float*)d_in[4];
    const float* Wh       = (const float*)d_in[5];
    const float* gamma    = (const float*)d_in[6];
    const float* beta     = (const float*)d_in[7];
    float* out = (float*)d_out;

    float* ws   = (float*)d_ws;
    float* dH2  = ws;            // 4096 floats
    float* logv = ws + 4096;     // 262144 floats

    k_hyp<<<1024, 256, 0, stream>>>(curr_hyp, demo_hyp, dH2, logv);
    k_main<<<512, 512, 0, stream>>>(curr_rho, demo_rho, curr_hyp, dH2, logv,
                                    We, Wh, gamma, beta, out);
}